// Round 1
// baseline (13457.979 us; speedup 1.0000x reference)
//
#include <hip/hip_runtime.h>

#define T_STEPS 2048
#define H       500
#define E       300
#define NCLS    20
#define G0      50      // layer-0 groups, 10 units each
#define G1      100     // layer-1 groups, 5 units each
#define HP      512     // padded h stride in workspace
#define C0      896     // L0 cols: [0,300)=x, [300,320)=0, [320,820)=h, [820,896)=0
#define C1      1024    // L1 cols: [0,500)=h0, [500,512)=0, [512,1012)=h1, [1012,1024)=0
#define R0      40      // gate rows per L0 group
#define R1      20      // gate rows per L1 group
#define U0      10
#define U1      5
#define NT      320     // 5 waves

__device__ __forceinline__ float sigm_(float x) {
    return 1.0f / (1.0f + __expf(-x));
}
__device__ __forceinline__ float tanh_(float x) {
    // robust: no inf/inf NaN for large |x|
    return 2.0f / (1.0f + __expf(-2.0f * x)) - 1.0f;
}

__global__ void lstm_init(float* h0s, float* h1s, int* cnt0, int* cnt1) {
    int i = blockIdx.x * blockDim.x + threadIdx.x;
    if (i < HP) {
        __hip_atomic_store(&h0s[i], 0.0f, __ATOMIC_RELAXED, __HIP_MEMORY_SCOPE_AGENT);
        __hip_atomic_store(&h1s[i], 0.0f, __ATOMIC_RELAXED, __HIP_MEMORY_SCOPE_AGENT);
    }
    if (i <= T_STEPS) {
        __hip_atomic_store(&cnt0[i], (i == 0) ? G0 : 0, __ATOMIC_RELAXED, __HIP_MEMORY_SCOPE_AGENT);
        __hip_atomic_store(&cnt1[i], (i == 0) ? G1 : 0, __ATOMIC_RELAXED, __HIP_MEMORY_SCOPE_AGENT);
    }
}

__launch_bounds__(NT)
__global__ void lstm_main(
    const int* __restrict__ seq, const float* __restrict__ emb,
    const float* __restrict__ Wih0, const float* __restrict__ Whh0,
    const float* __restrict__ bih0, const float* __restrict__ bhh0,
    const float* __restrict__ Wih1, const float* __restrict__ Whh1,
    const float* __restrict__ bih1, const float* __restrict__ bhh1,
    const float* __restrict__ fcW, const float* __restrict__ fcb,
    float* __restrict__ out,
    float* h0s, float* h1s, int* cnt0, int* cnt1)
{
    __shared__ float Wl[R0 * C0];   // 143360 B; L1 uses first R1*C1 = 20480 floats
    __shared__ float v[C1];
    __shared__ float gbuf[R0];
    __shared__ float bias[R0];

    const int tid = threadIdx.x;
    const int blk = blockIdx.x;

    if (blk < G0) {
        // ========================= layer 0 =========================
        const int g = blk;
        for (int e = tid; e < R0 * (C0 / 4); e += NT) {
            int r = e / (C0 / 4);
            int c = (e - r * (C0 / 4)) * 4;
            int gate = r / U0, u = r - gate * U0;
            int Rg = gate * H + g * U0 + u;
            float4 val;
            if (c < E)                    val = *(const float4*)&Wih0[(size_t)Rg * E + c];
            else if (c >= 320 && c < 820) val = *(const float4*)&Whh0[(size_t)Rg * H + (c - 320)];
            else                          val = make_float4(0.f, 0.f, 0.f, 0.f);
            *(float4*)&Wl[r * C0 + c] = val;
        }
        if (tid < R0) {
            int gate = tid / U0, u = tid - gate * U0;
            int Rg = gate * H + g * U0 + u;
            bias[tid] = bih0[Rg] + bhh0[Rg];
        }
        if (tid < 20) v[300 + tid] = 0.f;
        if (tid < 76) v[820 + tid] = 0.f;
        __syncthreads();

        const int q = tid >> 5;   // 0..9 (row quad)
        const int j = tid & 31;   // lane within quad
        float cst = 0.f;          // cell state for unit tid (tid < U0)

        for (int t = 1; t <= T_STEPS; ++t) {
            // issue x load before the spin so HBM latency hides under the wait
            int erow = seq[t - 1];
            float4 xr = make_float4(0.f, 0.f, 0.f, 0.f);
            if (tid < 75) xr = *(const float4*)&emb[(size_t)erow * E + tid * 4];
            if (tid < 64) {
                while (__hip_atomic_load(&cnt0[t - 1], __ATOMIC_ACQUIRE, __HIP_MEMORY_SCOPE_AGENT) < G0) {}
            }
            __syncthreads();
            if (tid < 75) *(float4*)&v[tid * 4] = xr;
            {
                const float* hsrc = &h0s[(size_t)(t - 1) * HP];
                for (int idx = tid; idx < H; idx += NT)
                    v[320 + idx] = __hip_atomic_load(&hsrc[idx], __ATOMIC_RELAXED, __HIP_MEMORY_SCOPE_AGENT);
            }
            __syncthreads();

            float a0 = 0.f, a1 = 0.f, a2 = 0.f, a3 = 0.f;
            #pragma unroll
            for (int k = 0; k < 7; ++k) {
                int c4 = (k * 32 + j) * 4;
                float4 xv = *(const float4*)&v[c4];
                const float* wp = &Wl[(q * 4) * C0 + c4];
                float4 w0 = *(const float4*)(wp);
                float4 w1 = *(const float4*)(wp + C0);
                float4 w2 = *(const float4*)(wp + 2 * C0);
                float4 w3 = *(const float4*)(wp + 3 * C0);
                a0 += w0.x * xv.x + w0.y * xv.y + w0.z * xv.z + w0.w * xv.w;
                a1 += w1.x * xv.x + w1.y * xv.y + w1.z * xv.z + w1.w * xv.w;
                a2 += w2.x * xv.x + w2.y * xv.y + w2.z * xv.z + w2.w * xv.w;
                a3 += w3.x * xv.x + w3.y * xv.y + w3.z * xv.z + w3.w * xv.w;
            }
            #pragma unroll
            for (int m = 16; m >= 1; m >>= 1) {
                a0 += __shfl_xor(a0, m, 64);
                a1 += __shfl_xor(a1, m, 64);
                a2 += __shfl_xor(a2, m, 64);
                a3 += __shfl_xor(a3, m, 64);
            }
            if (j == 0) {
                int r = q * 4;
                gbuf[r + 0] = a0 + bias[r + 0];
                gbuf[r + 1] = a1 + bias[r + 1];
                gbuf[r + 2] = a2 + bias[r + 2];
                gbuf[r + 3] = a3 + bias[r + 3];
            }
            __syncthreads();
            if (tid < U0) {
                float gi = gbuf[tid], gf = gbuf[U0 + tid], gg = gbuf[2 * U0 + tid], go = gbuf[3 * U0 + tid];
                float iv = sigm_(gi), fv = sigm_(gf), gv = tanh_(gg), ov = sigm_(go);
                cst = fv * cst + iv * gv;
                float hv = ov * tanh_(cst);
                __hip_atomic_store(&h0s[(size_t)t * HP + g * U0 + tid], hv,
                                   __ATOMIC_RELAXED, __HIP_MEMORY_SCOPE_AGENT);
            }
            __syncthreads();
            if (tid == 0)
                __hip_atomic_fetch_add(&cnt0[t], 1, __ATOMIC_RELEASE, __HIP_MEMORY_SCOPE_AGENT);
        }
    } else {
        // ========================= layer 1 =========================
        const int g = blk - G0;
        for (int e = tid; e < R1 * (C1 / 4); e += NT) {
            int r = e / (C1 / 4);
            int c = (e - r * (C1 / 4)) * 4;
            int gate = r / U1, u = r - gate * U1;
            int Rg = gate * H + g * U1 + u;
            float4 val;
            if (c < H)                     val = *(const float4*)&Wih1[(size_t)Rg * H + c];
            else if (c >= 512 && c < 1012) val = *(const float4*)&Whh1[(size_t)Rg * H + (c - 512)];
            else                           val = make_float4(0.f, 0.f, 0.f, 0.f);
            *(float4*)&Wl[r * C1 + c] = val;
        }
        if (tid < R1) {
            int gate = tid / U1, u = tid - gate * U1;
            int Rg = gate * H + g * U1 + u;
            bias[tid] = bih1[Rg] + bhh1[Rg];
        }
        if (tid < 12) { v[500 + tid] = 0.f; v[1012 + tid] = 0.f; }
        __syncthreads();

        const int q = tid >> 6;   // 0..4
        const int j = tid & 63;
        float cst = 0.f;

        for (int t = 1; t <= T_STEPS; ++t) {
            if (tid < 64) {
                while (__hip_atomic_load(&cnt0[t], __ATOMIC_ACQUIRE, __HIP_MEMORY_SCOPE_AGENT) < G0) {}
                while (__hip_atomic_load(&cnt1[t - 1], __ATOMIC_ACQUIRE, __HIP_MEMORY_SCOPE_AGENT) < G1) {}
            }
            __syncthreads();
            {
                const float* h0src = &h0s[(size_t)t * HP];
                const float* h1src = &h1s[(size_t)(t - 1) * HP];
                for (int idx = tid; idx < H; idx += NT) {
                    v[idx]       = __hip_atomic_load(&h0src[idx], __ATOMIC_RELAXED, __HIP_MEMORY_SCOPE_AGENT);
                    v[512 + idx] = __hip_atomic_load(&h1src[idx], __ATOMIC_RELAXED, __HIP_MEMORY_SCOPE_AGENT);
                }
            }
            __syncthreads();

            float a0 = 0.f, a1 = 0.f, a2 = 0.f, a3 = 0.f;
            #pragma unroll
            for (int k = 0; k < 4; ++k) {
                int c4 = (k * 64 + j) * 4;
                float4 xv = *(const float4*)&v[c4];
                const float* wp = &Wl[(q * 4) * C1 + c4];
                float4 w0 = *(const float4*)(wp);
                float4 w1 = *(const float4*)(wp + C1);
                float4 w2 = *(const float4*)(wp + 2 * C1);
                float4 w3 = *(const float4*)(wp + 3 * C1);
                a0 += w0.x * xv.x + w0.y * xv.y + w0.z * xv.z + w0.w * xv.w;
                a1 += w1.x * xv.x + w1.y * xv.y + w1.z * xv.z + w1.w * xv.w;
                a2 += w2.x * xv.x + w2.y * xv.y + w2.z * xv.z + w2.w * xv.w;
                a3 += w3.x * xv.x + w3.y * xv.y + w3.z * xv.z + w3.w * xv.w;
            }
            #pragma unroll
            for (int m = 32; m >= 1; m >>= 1) {
                a0 += __shfl_xor(a0, m, 64);
                a1 += __shfl_xor(a1, m, 64);
                a2 += __shfl_xor(a2, m, 64);
                a3 += __shfl_xor(a3, m, 64);
            }
            if (j == 0) {
                int r = q * 4;
                gbuf[r + 0] = a0 + bias[r + 0];
                gbuf[r + 1] = a1 + bias[r + 1];
                gbuf[r + 2] = a2 + bias[r + 2];
                gbuf[r + 3] = a3 + bias[r + 3];
            }
            __syncthreads();
            if (tid < U1) {
                float gi = gbuf[tid], gf = gbuf[U1 + tid], gg = gbuf[2 * U1 + tid], go = gbuf[3 * U1 + tid];
                float iv = sigm_(gi), fv = sigm_(gf), gv = tanh_(gg), ov = sigm_(go);
                cst = fv * cst + iv * gv;
                float hv = ov * tanh_(cst);
                __hip_atomic_store(&h1s[(size_t)t * HP + g * U1 + tid], hv,
                                   __ATOMIC_RELAXED, __HIP_MEMORY_SCOPE_AGENT);
            }
            __syncthreads();
            if (tid == 0)
                __hip_atomic_fetch_add(&cnt1[t], 1, __ATOMIC_RELEASE, __HIP_MEMORY_SCOPE_AGENT);
        }

        // final FC on h1[T] by layer-1 group 0
        if (g == 0) {
            if (tid < 64) {
                while (__hip_atomic_load(&cnt1[T_STEPS], __ATOMIC_ACQUIRE, __HIP_MEMORY_SCOPE_AGENT) < G1) {}
            }
            __syncthreads();
            int rowc = tid >> 4;   // 0..19
            int jj = tid & 15;
            float acc = 0.f;
            const float* hlast = &h1s[(size_t)T_STEPS * HP];
            for (int k2 = 0; k2 < 32; ++k2) {
                int c = jj + 16 * k2;
                if (c < H) {
                    float hvv = __hip_atomic_load(&hlast[c], __ATOMIC_RELAXED, __HIP_MEMORY_SCOPE_AGENT);
                    acc += fcW[rowc * H + c] * hvv;
                }
            }
            #pragma unroll
            for (int m = 8; m >= 1; m >>= 1) acc += __shfl_xor(acc, m, 64);
            if (jj == 0) out[rowc] = acc + fcb[rowc];
        }
    }
}

extern "C" void kernel_launch(void* const* d_in, const int* in_sizes, int n_in,
                              void* d_out, int out_size, void* d_ws, size_t ws_size,
                              hipStream_t stream)
{
    const int*   seq  = (const int*)d_in[0];
    const float* emb  = (const float*)d_in[1];
    const float* Wih0 = (const float*)d_in[2];
    const float* Whh0 = (const float*)d_in[3];
    const float* bih0 = (const float*)d_in[4];
    const float* bhh0 = (const float*)d_in[5];
    const float* Wih1 = (const float*)d_in[6];
    const float* Whh1 = (const float*)d_in[7];
    const float* bih1 = (const float*)d_in[8];
    const float* bhh1 = (const float*)d_in[9];
    const float* fcW  = (const float*)d_in[10];
    const float* fcb  = (const float*)d_in[11];
    float* out = (float*)d_out;

    char* ws = (char*)d_ws;
    float* h0s = (float*)ws;
    float* h1s = (float*)(ws + (size_t)(T_STEPS + 1) * HP * sizeof(float));
    int*   cnt0 = (int*)(ws + 2 * (size_t)(T_STEPS + 1) * HP * sizeof(float));
    int*   cnt1 = cnt0 + (T_STEPS + 1);

    hipLaunchKernelGGL(lstm_init, dim3(9), dim3(256), 0, stream, h0s, h1s, cnt0, cnt1);
    hipLaunchKernelGGL(lstm_main, dim3(G0 + G1), dim3(NT), 0, stream,
                       seq, emb, Wih0, Whh0, bih0, bhh0, Wih1, Whh1, bih1, bhh1,
                       fcW, fcb, out, h0s, h1s, cnt0, cnt1);
}